// Round 22
// baseline (88.800 us; speedup 1.0000x reference)
//
#include <hip/hip_runtime.h>
#include <hip/hip_bf16.h>

#define DIN 64
#define DOUT 62
#define ICH 32
#define OCH 64

typedef __bf16 bf16x8 __attribute__((ext_vector_type(8)));
typedef float f32x4 __attribute__((ext_vector_type(4)));
typedef float f32x8 __attribute__((ext_vector_type(8)));
typedef float f32x16 __attribute__((ext_vector_type(16)));

#define AS1U(p) ((const __attribute__((address_space(1))) unsigned int*)(p))
#define AS3U(p) ((__attribute__((address_space(3))) unsigned int*)(p))

// ---------- merged prep: one launch does both W and x repack (verified R21) ----------
// Wre3[(((tap*2+mt)*2+kh)*64+lane)*8+j] = bf16( W[oc=mt*32+(lane&31)][ic=kh*16+(lane>>5)*8+j][tap] )
// xp SLICE-MAJOR: xp[b][z][y][s(4)][w(64)][8ic] bf16 (16B packets, fragment-linear).
__global__ void prep_all(const float* __restrict__ x, const float* __restrict__ W,
                         unsigned short* __restrict__ Wre3, unsigned short* __restrict__ xp) {
    const int bid = blockIdx.x;
    if (bid < 8192) {
        int idx = bid * 256 + threadIdx.x;           // 2,097,152 packets
        int w = idx & 63;
        int s = (idx >> 6) & 3;
        int y = (idx >> 8) & 63;
        int z = (idx >> 14) & 63;
        int b = idx >> 20;
        const float* xb = x + ((size_t)(b * ICH + s * 8)) * 262144 + (size_t)z * 4096 + y * 64 + w;
        bf16x8 pk;
#pragma unroll
        for (int j = 0; j < 8; ++j)
            pk[j] = (__bf16)xb[(size_t)j * 262144];
        ((int4*)xp)[idx] = __builtin_bit_cast(int4, pk);
    } else {
        int idx = (bid - 8192) * 256 + threadIdx.x;  // 55,296 elements
        if (idx < 27 * OCH * ICH) {
            int j    = idx & 7;
            int lane = (idx >> 3) & 63;
            int kh   = (idx >> 9) & 1;
            int mt   = (idx >> 10) & 1;
            int tap  = idx >> 11;
            int oc   = mt * 32 + (lane & 31);
            int ic   = kh * 16 + (lane >> 5) * 8 + j;
            float v  = W[((size_t)oc * ICH + ic) * 27 + tap];
            Wre3[idx] = __builtin_bit_cast(unsigned short, (__bf16)v);
        }
    }
}

// ---------- main: R16 skeleton, 8 waves = (2 oc-halves) x (4 rows) ----------
// Identical plane layout / barriers / staging map to the replay-verified R16 kernel;
// each wave loads only its oc-half of A (2 KB/tap) -> per-CU TA traffic drops 48->32 KB/tap.
// 512 thr, launch_bounds(512,4): 128 regs/wave, 2 blocks/CU = 16 waves/CU = 4 waves/SIMD.
__global__ __launch_bounds__(512, 4) void conv3d_mfma_pk(
    const unsigned short* __restrict__ Wre3,
    const unsigned short* __restrict__ xp,
    float* __restrict__ out)
{
    __shared__ char xs[2 * 24576 + 256];             // 2 plane bufs + guard (R16 layout)

    const int tid  = threadIdx.x;
    const int lane = tid & 63;
    const int wave = tid >> 6;                       // 0..7
    const int rloc  = wave & 3;                      // h row within tile
    const int ohalf = wave >> 2;                     // oc half (0/1)

    // bijective XCD-aware swizzle (nwg = 1984 = 8*248 exactly)
    const int orig = blockIdx.x;
    const int lid  = (orig & 7) * 248 + (orig >> 3);
    const int ht = lid & 15;
    const int rr = lid >> 4;
    const int d  = rr % DOUT;
    const int b  = rr / DOUT;
    const int h0 = ht * 4;

    const int l31 = lane & 31;                       // w-in-tile / oc-in-tile
    const int lhi = lane >> 5;                       // k-subgroup (8 ic) within k-half

    // one 1KB chunk (c = y*4+s): 8 waves x 3 chunks = 24 (same map as R16's 4x6)
    auto stage_chunk = [&](char* buf, int z, int i) {
        int c  = wave * 3 + i;                       // 0..23
        int yl = c >> 2;                             // y row 0..5
        int sl = c & 3;                              // ic-slice
        int srow = h0 + yl; if (srow > 63) srow = 63;   // clamped rows feed only discarded h
        const unsigned short* src =
            xp + ((((size_t)(b * DIN + z) * DIN + srow) * 4 + sl) * 64) * 8 + lane * 8;
        __builtin_amdgcn_global_load_lds(AS1U(src), AS3U(buf + c * 1024), 16, 0, 0);
    };
    // A for THIS oc-half: 2 coalesced dwordx4 per tap (tap stride 256 int4)
    auto loadA = [&](int tap, int4* af) {
        const int4* wp = (const int4*)Wre3 + (size_t)tap * 256 + ohalf * 128 + lane;
#pragma unroll
        for (int kh = 0; kh < 2; ++kh)
            af[kh] = wp[kh * 64];
    };
    auto readB = [&](const char* buf, int ky, int kx, int4* dst) {   // 4 x ds_read_b128
#pragma unroll
        for (int kh = 0; kh < 2; ++kh) {
            const int g = kh * 2 + lhi;
#pragma unroll
            for (int nt = 0; nt < 2; ++nt) {
                int wb = nt * 32 + l31 + kx;
                if (wb > 63) wb = 63;                // cols 62/63 only (discarded outputs)
                dst[kh * 2 + nt] = *(const int4*)(buf + (((rloc + ky) * 4 + g) * 64 + wb) * 16);
            }
        }
    };

    char* bufA = xs;
    char* bufB = xs + 24576;

#pragma unroll
    for (int i = 0; i < 3; ++i) stage_chunk(bufA, d, i);   // plane kz=0 (burst, once)
    int4 af[3][2];
    loadA(0, af[0]);
    loadA(1, af[1]);

    f32x16 acc[2];                                   // [nt]; M fixed = this oc-half
#pragma unroll
    for (int nt = 0; nt < 2; ++nt)
#pragma unroll
        for (int r = 0; r < 16; ++r) acc[nt][r] = 0.f;

    __syncthreads();                                 // plane 0 ready

    int4 bfr[2][4];
    const bool oddw = (wave & 1) != 0;               // wave-uniform de-phase

#pragma unroll                                        // kz static -> all indices compile-time
    for (int kz = 0; kz < 3; ++kz) {
        char* cur = (kz & 1) ? bufB : bufA;
        char* nxt = (kz & 1) ? bufA : bufB;
        readB(cur, 0, 0, bfr[0]);                    // per-segment B prologue

#pragma unroll
        for (int t = 0; t < 9; ++t) {
            const int T = kz * 9 + t;
            if (oddw) {
                if (t < 8)  readB(cur, (t + 1) / 3, (t + 1) % 3, bfr[(t + 1) & 1]);
                if (T < 25) loadA(T + 2, af[(T + 2) % 3]);       // A: 2-deep
            } else {
                if (T < 25) loadA(T + 2, af[(T + 2) % 3]);
                if (t < 8)  readB(cur, (t + 1) / 3, (t + 1) % 3, bfr[(t + 1) & 1]);
            }
            if (kz < 2 && t < 3) stage_chunk(nxt, d + kz + 1, t);   // after loads (vmcnt order)

#pragma unroll
            for (int kh = 0; kh < 2; ++kh)           // acc chain distance 2; 4 waves/SIMD hide
#pragma unroll
                for (int nt = 0; nt < 2; ++nt)
                    acc[nt] = __builtin_amdgcn_mfma_f32_32x32x16_bf16(
                        __builtin_bit_cast(bf16x8, af[T % 3][kh]),
                        __builtin_bit_cast(bf16x8, bfr[t & 1][kh * 2 + nt]),
                        acc[nt], 0, 0, 0);
        }
        if (kz < 2) __syncthreads();                 // next plane landed; cur free
    }

    // ---- store: D col=lane&31 -> w, row=(r&3)+8*(r>>2)+4*(lane>>5) -> oc (this oc-half) ----
    const int h = h0 + rloc;
    if (h < DOUT) {
#pragma unroll
        for (int r = 0; r < 16; ++r) {
            int oc = ohalf * 32 + (r & 3) + 8 * (r >> 2) + 4 * lhi;
            size_t ob = ((((size_t)b * OCH + oc) * DOUT + d) * DOUT + h) * DOUT;
#pragma unroll
            for (int nt = 0; nt < 2; ++nt) {
                int ww = nt * 32 + l31;
                if (ww < DOUT) out[ob + ww] = acc[nt][r];
            }
        }
    }
}

// ---------- fallback (ws too small): reg-staged 16x16 kernel, f32 W direct ----------
__global__ __launch_bounds__(256, 3) void conv3d_mfma_fb(
    const float* __restrict__ x, const float* __restrict__ W,
    float* __restrict__ out)
{
    __shared__ char xs[2][6 * 66 * 64];

    const int tid  = threadIdx.x;
    const int lane = tid & 63;
    const int wave = tid >> 6;

    const int orig = blockIdx.x;
    const int lid  = (orig & 7) * 248 + (orig >> 3);
    const int ht = lid & 15;
    const int rr = lid >> 4;
    const int d  = rr % DOUT;
    const int b  = rr / DOUT;
    const int h0 = ht * 4;

    const int wlo = lane & 15;
    const int whi = lane >> 4;
    const int row = wave;

    const int icg  = wave;
    const int w    = lane;
    const int slot = icg ^ ((w >> 1) & 3);

    auto issueRow = [&](int z, int y) -> f32x8 {
        int gy = h0 + y; if (gy > 63) gy = 63;
        const float* xp2 = x + (((size_t)(b * ICH + icg * 8) * DIN + z) * DIN + gy) * DIN + w;
        f32x8 s;
#pragma unroll
        for (int j = 0; j < 8; ++j) s[j] = xp2[(size_t)j * DIN * DIN * DIN];
        return s;
    };
    auto writeRow = [&](char* buf, int y, f32x8 s) {
        bf16x8 pk;
#pragma unroll
        for (int j = 0; j < 8; ++j) pk[j] = (__bf16)s[j];
        *(int4*)(buf + ((y * 66 + w) * 64 + slot * 16)) = __builtin_bit_cast(int4, pk);
    };
    auto loadA = [&](int tap, int4* af) {
#pragma unroll
        for (int mt = 0; mt < 4; ++mt) {
            const float* wp = W + ((size_t)(mt * 16 + wlo) * ICH + whi * 8) * 27 + tap;
            bf16x8 t;
#pragma unroll
            for (int j = 0; j < 8; ++j) t[j] = (__bf16)wp[j * 27];
            af[mt] = __builtin_bit_cast(int4, t);
        }
    };
    auto readB = [&](const char* buf, int ky, int kx, int4* dst) {
#pragma unroll
        for (int nt = 0; nt < 4; ++nt) {
            int wb = nt * 16 + wlo + kx;
            int sl = whi ^ ((wb >> 1) & 3);
            dst[nt] = *(const int4*)(buf + (((row + ky) * 66 + wb) * 64 + sl * 16));
        }
    };

    if (tid < 96) {
        int bu = tid / 48, q2 = tid % 48;
        int y = q2 >> 3, q = q2 & 7;
        int w2 = 64 + (q >> 2), sl = q & 3;
        *(int4*)(xs[bu] + ((y * 66 + w2) * 64 + sl * 16)) = int4{0, 0, 0, 0};
    }
    {
        f32x8 s0 = issueRow(d, 0), s1 = issueRow(d, 1), s2 = issueRow(d, 2);
        writeRow(xs[0], 0, s0); s0 = issueRow(d, 3);
        writeRow(xs[0], 1, s1); s1 = issueRow(d, 4);
        writeRow(xs[0], 2, s2); s2 = issueRow(d, 5);
        writeRow(xs[0], 3, s0); writeRow(xs[0], 4, s1); writeRow(xs[0], 5, s2);
    }
    int4 af[2][4];
    loadA(0, af[0]);
    __syncthreads();

    f32x4 acc[4][4];
#pragma unroll
    for (int mt = 0; mt < 4; ++mt)
#pragma unroll
        for (int nt = 0; nt < 4; ++nt)
            acc[mt][nt] = f32x4{0.f, 0.f, 0.f, 0.f};

    int4 bfr[2][4];

#pragma unroll
    for (int kz = 0; kz < 3; ++kz) {
        char* cur = xs[kz & 1];
        char* nxt = xs[(kz + 1) & 1];
        f32x8 s0, s1, s2;
        readB(cur, 0, 0, bfr[0]);
#pragma unroll
        for (int t = 0; t < 9; ++t) {
            const int T = kz * 9 + t;
            if (T < 26) loadA(T + 1, af[(T + 1) & 1]);
            if (t < 8)  readB(cur, (t + 1) / 3, (t + 1) % 3, bfr[(t + 1) & 1]);
            if (kz < 2) {
                if (t == 3) writeRow(nxt, 0, s0);
                if (t == 4) writeRow(nxt, 1, s1);
                if (t == 5) writeRow(nxt, 2, s2);
                if (t == 6) writeRow(nxt, 3, s0);
                if (t == 7) writeRow(nxt, 4, s1);
                if (t == 8) writeRow(nxt, 5, s2);
                if (t == 0) s0 = issueRow(d + kz + 1, 0);
                if (t == 1) s1 = issueRow(d + kz + 1, 1);
                if (t == 2) s2 = issueRow(d + kz + 1, 2);
                if (t == 3) s0 = issueRow(d + kz + 1, 3);
                if (t == 4) s1 = issueRow(d + kz + 1, 4);
                if (t == 5) s2 = issueRow(d + kz + 1, 5);
            }
#pragma unroll
            for (int mt = 0; mt < 4; ++mt)
#pragma unroll
                for (int nt = 0; nt < 4; ++nt)
                    acc[mt][nt] = __builtin_amdgcn_mfma_f32_16x16x32_bf16(
                        __builtin_bit_cast(bf16x8, af[T & 1][mt]),
                        __builtin_bit_cast(bf16x8, bfr[t & 1][nt]),
                        acc[mt][nt], 0, 0, 0);
        }
        if (kz < 2) __syncthreads();
    }

    const int h = h0 + row;
    if (h < DOUT) {
#pragma unroll
        for (int mt = 0; mt < 4; ++mt) {
#pragma unroll
            for (int r = 0; r < 4; ++r) {
                int oc = mt * 16 + whi * 4 + r;
                size_t ob = ((((size_t)b * OCH + oc) * DOUT + d) * DOUT + h) * DOUT;
#pragma unroll
                for (int nt = 0; nt < 4; ++nt) {
                    int ww = nt * 16 + wlo;
                    if (ww < DOUT) out[ob + ww] = acc[mt][nt][r];
                }
            }
        }
    }
}

extern "C" void kernel_launch(void* const* d_in, const int* in_sizes, int n_in,
                              void* d_out, int out_size, void* d_ws, size_t ws_size,
                              hipStream_t stream) {
    const float* x = (const float*)d_in[0];
    const float* W = (const float*)d_in[1];
    float* out = (float*)d_out;

    const size_t wre_elems = (size_t)27 * OCH * ICH;             // 55,296 ushort
    const size_t xp_elems  = (size_t)2 * DIN * DIN * DIN * ICH;  // 16,777,216 ushort
    const size_t need = (wre_elems + xp_elems) * 2 + 256;

    if (ws_size >= need) {
        unsigned short* Wre3 = (unsigned short*)d_ws;
        unsigned short* xp   = Wre3 + wre_elems;
        prep_all<<<dim3(8192 + 216), 256, 0, stream>>>(x, W, Wre3, xp);
        conv3d_mfma_pk<<<dim3(2 * DOUT * 16), 512, 0, stream>>>(Wre3, xp, out);  // 1984 = 8*248
    } else {
        conv3d_mfma_fb<<<dim3(2 * DOUT * 16), 256, 0, stream>>>(x, W, out);
    }
}

// Round 23
// 85.292 us; speedup vs baseline: 1.0411x; 1.0411x over previous
//
#include <hip/hip_runtime.h>
#include <hip/hip_bf16.h>

#define DIN 64
#define DOUT 62
#define ICH 32
#define OCH 64

typedef __bf16 bf16x8 __attribute__((ext_vector_type(8)));
typedef float f32x4 __attribute__((ext_vector_type(4)));
typedef float f32x8 __attribute__((ext_vector_type(8)));
typedef float f32x16 __attribute__((ext_vector_type(16)));

#define AS1U(p) ((const __attribute__((address_space(1))) unsigned int*)(p))
#define AS3U(p) ((__attribute__((address_space(3))) unsigned int*)(p))

// ---------- merged prep: one launch does both W and x repack (verified R21) ----------
// Wre3[(((tap*2+mt)*2+kh)*64+lane)*8+j] = bf16( W[oc=mt*32+(lane&31)][ic=kh*16+(lane>>5)*8+j][tap] )
// xp SLICE-MAJOR: xp[b][z][y][s(4)][w(64)][8ic] bf16 (16B packets, fragment-linear).
__global__ void prep_all(const float* __restrict__ x, const float* __restrict__ W,
                         unsigned short* __restrict__ Wre3, unsigned short* __restrict__ xp) {
    const int bid = blockIdx.x;
    if (bid < 8192) {
        int idx = bid * 256 + threadIdx.x;           // 2,097,152 packets
        int w = idx & 63;
        int s = (idx >> 6) & 3;
        int y = (idx >> 8) & 63;
        int z = (idx >> 14) & 63;
        int b = idx >> 20;
        const float* xb = x + ((size_t)(b * ICH + s * 8)) * 262144 + (size_t)z * 4096 + y * 64 + w;
        bf16x8 pk;
#pragma unroll
        for (int j = 0; j < 8; ++j)
            pk[j] = (__bf16)xb[(size_t)j * 262144];
        ((int4*)xp)[idx] = __builtin_bit_cast(int4, pk);
    } else {
        int idx = (bid - 8192) * 256 + threadIdx.x;  // 55,296 elements
        if (idx < 27 * OCH * ICH) {
            int j    = idx & 7;
            int lane = (idx >> 3) & 63;
            int kh   = (idx >> 9) & 1;
            int mt   = (idx >> 10) & 1;
            int tap  = idx >> 11;
            int oc   = mt * 32 + (lane & 31);
            int ic   = kh * 16 + (lane >> 5) * 8 + j;
            float v  = W[((size_t)oc * ICH + ic) * 27 + tap];
            Wre3[idx] = __builtin_bit_cast(unsigned short, (__bf16)v);
        }
    }
}

// ---------- main: d-pair kernel — each block computes outputs d0 and d0+1 ----------
// Block = 256 thr, 4 waves = (2 oc-halves) x (2 h-rows); tile 2h x 64oc x 64w x 2d.
// 4 plane-segments z = d0..d0+3; B fragment per (z,ky,kx,row) is SHARED by both outputs
// (halves ds_reads per MFMA); staging 4 planes / 2 outputs (-33%).  A taps differ per
// output (kz = s - o), 1-deep parity prefetch, fully static.  Same 2-buffer /
// 1-barrier-per-segment discipline as the replay-verified R16 kernel.
__global__ __launch_bounds__(256, 3) void conv3d_mfma_pk(
    const unsigned short* __restrict__ Wre3,
    const unsigned short* __restrict__ xp,
    float* __restrict__ out)
{
    __shared__ char xs[2 * 16384 + 256];             // 2 x 16KB plane bufs + guard

    const int tid  = threadIdx.x;
    const int lane = tid & 63;
    const int wave = tid >> 6;                       // 0..3
    const int rloc  = wave & 1;                      // h row within tile
    const int ohalf = wave >> 1;                     // oc half (0/1)

    // general bijective XCD swizzle (m204): nwg = 1922 = 8*240 + 2
    const int orig = blockIdx.x;
    const int xcd  = orig & 7;
    const int kk   = orig >> 3;
    const int lid  = (xcd < 2 ? xcd * 241 : 482 + (xcd - 2) * 240) + kk;
    const int ht = lid % 31;                         // 31 h-tiles x 2 rows = 62 exact
    const int rr = lid / 31;
    const int dp = rr % 31;                          // 31 d-pairs x 2 = 62 exact
    const int b  = rr / 31;
    const int d0 = dp * 2;
    const int h0 = ht * 2;

    const int l31 = lane & 31;                       // w-in-tile / oc-in-tile
    const int lhi = lane >> 5;                       // k-subgroup (8 ic) within k-half

    // one 1KB chunk (c = y*4+s) of a 16KB plane [4y][4s][64w][16B]; rows h0..h0+3 <= 63
    auto stage_chunk = [&](char* buf, int z, int i) {
        int c  = wave * 4 + i;                       // 0..15
        int yl = c >> 2;                             // 0..3
        int sl = c & 3;
        const unsigned short* src =
            xp + ((((size_t)(b * DIN + z) * DIN + (h0 + yl)) * 4 + sl) * 64) * 8 + lane * 8;
        __builtin_amdgcn_global_load_lds(AS1U(src), AS3U(buf + c * 1024), 16, 0, 0);
    };
    // A for THIS oc-half: 2 coalesced dwordx4 (tap stride 256 int4)
    auto loadA = [&](int tap, int4* a2) {
        const int4* wp = (const int4*)Wre3 + (size_t)tap * 256 + ohalf * 128 + lane;
        a2[0] = wp[0];
        a2[1] = wp[64];
    };
    // B shared by both outputs: dst[kh*2+nt], 4 x ds_read_b128 (contiguous 512B runs)
    auto readB = [&](const char* buf, int ky, int kx, int4* dst) {
#pragma unroll
        for (int kh = 0; kh < 2; ++kh) {
            const int sg = kh * 2 + lhi;
#pragma unroll
            for (int nt = 0; nt < 2; ++nt) {
                int wb = nt * 32 + l31 + kx;
                if (wb > 63) wb = 63;                // cols 62/63 only (discarded outputs)
                dst[kh * 2 + nt] = *(const int4*)(buf + (((rloc + ky) * 4 + sg) * 64 + wb) * 16);
            }
        }
    };

#pragma unroll
    for (int i = 0; i < 4; ++i) stage_chunk(xs, d0, i);    // plane z = d0 (burst, once)
    int4 afA[2][2], afB[2][2];                       // [parity][kh]; A for out0 / out1
    loadA(0, afA[0]);                                // g=0: out0 tap 0

    f32x16 acc[2][2];                                // [out][nt]
#pragma unroll
    for (int o = 0; o < 2; ++o)
#pragma unroll
        for (int nt = 0; nt < 2; ++nt)
#pragma unroll
            for (int r = 0; r < 16; ++r) acc[o][nt][r] = 0.f;

    __syncthreads();                                 // plane 0 ready

    int4 bfr[2][4];

#pragma unroll                                        // 4 segments, all indices compile-time
    for (int s = 0; s < 4; ++s) {
        char* cur = xs + (s & 1) * 16384;
        char* nxt = xs + ((s + 1) & 1) * 16384;
        readB(cur, 0, 0, bfr[0]);                    // per-segment B prologue

#pragma unroll
        for (int it = 0; it < 9; ++it) {
            const int g = s * 9 + it;                // global iteration 0..35
            const int p = g & 1;

            // prefetch next iteration's A (parity-rotated, compile-time taps)
            if (g < 35) {
                const int sn  = (it == 8) ? s + 1 : s;
                const int itn = (it == 8) ? 0 : it + 1;
                if (sn <= 2) loadA(sn * 9 + itn, afA[p ^ 1]);        // out0: kz = sn
                if (sn >= 1) loadA((sn - 1) * 9 + itn, afB[p ^ 1]);  // out1: kz = sn-1
            }
            if (it < 8) readB(cur, (it + 1) / 3, (it + 1) % 3, bfr[(it + 1) & 1]);
            if (s < 3 && it < 4) stage_chunk(nxt, d0 + s + 1, it);   // after loads (vmcnt order)

            if (s <= 2) {                            // out0 active (kz = s)
#pragma unroll
                for (int kh = 0; kh < 2; ++kh)
#pragma unroll
                    for (int nt = 0; nt < 2; ++nt)
                        acc[0][nt] = __builtin_amdgcn_mfma_f32_32x32x16_bf16(
                            __builtin_bit_cast(bf16x8, afA[p][kh]),
                            __builtin_bit_cast(bf16x8, bfr[it & 1][kh * 2 + nt]),
                            acc[0][nt], 0, 0, 0);
            }
            if (s >= 1) {                            // out1 active (kz = s-1)
#pragma unroll
                for (int kh = 0; kh < 2; ++kh)
#pragma unroll
                    for (int nt = 0; nt < 2; ++nt)
                        acc[1][nt] = __builtin_amdgcn_mfma_f32_32x32x16_bf16(
                            __builtin_bit_cast(bf16x8, afB[p][kh]),
                            __builtin_bit_cast(bf16x8, bfr[it & 1][kh * 2 + nt]),
                            acc[1][nt], 0, 0, 0);
            }
        }
        if (s < 3) __syncthreads();                  // next plane landed; cur free
    }

    // ---- store both outputs: D col=lane&31 -> w, row=(r&3)+8*(r>>2)+4*lhi -> oc ----
    const int h = h0 + rloc;                         // always < 62
#pragma unroll
    for (int o = 0; o < 2; ++o) {
        const int dd = d0 + o;                       // always < 62
#pragma unroll
        for (int r = 0; r < 16; ++r) {
            int oc = ohalf * 32 + (r & 3) + 8 * (r >> 2) + 4 * lhi;
            size_t ob = ((((size_t)b * OCH + oc) * DOUT + dd) * DOUT + h) * DOUT;
#pragma unroll
            for (int nt = 0; nt < 2; ++nt) {
                int ww = nt * 32 + l31;
                if (ww < DOUT) out[ob + ww] = acc[o][nt][r];
            }
        }
    }
}

// ---------- fallback (ws too small): reg-staged 16x16 kernel, f32 W direct ----------
__global__ __launch_bounds__(256, 3) void conv3d_mfma_fb(
    const float* __restrict__ x, const float* __restrict__ W,
    float* __restrict__ out)
{
    __shared__ char xs[2][6 * 66 * 64];

    const int tid  = threadIdx.x;
    const int lane = tid & 63;
    const int wave = tid >> 6;

    const int orig = blockIdx.x;
    const int lid  = (orig & 7) * 248 + (orig >> 3);
    const int ht = lid & 15;
    const int rr = lid >> 4;
    const int d  = rr % DOUT;
    const int b  = rr / DOUT;
    const int h0 = ht * 4;

    const int wlo = lane & 15;
    const int whi = lane >> 4;
    const int row = wave;

    const int icg  = wave;
    const int w    = lane;
    const int slot = icg ^ ((w >> 1) & 3);

    auto issueRow = [&](int z, int y) -> f32x8 {
        int gy = h0 + y; if (gy > 63) gy = 63;
        const float* xp2 = x + (((size_t)(b * ICH + icg * 8) * DIN + z) * DIN + gy) * DIN + w;
        f32x8 s;
#pragma unroll
        for (int j = 0; j < 8; ++j) s[j] = xp2[(size_t)j * DIN * DIN * DIN];
        return s;
    };
    auto writeRow = [&](char* buf, int y, f32x8 s) {
        bf16x8 pk;
#pragma unroll
        for (int j = 0; j < 8; ++j) pk[j] = (__bf16)s[j];
        *(int4*)(buf + ((y * 66 + w) * 64 + slot * 16)) = __builtin_bit_cast(int4, pk);
    };
    auto loadA = [&](int tap, int4* af) {
#pragma unroll
        for (int mt = 0; mt < 4; ++mt) {
            const float* wp = W + ((size_t)(mt * 16 + wlo) * ICH + whi * 8) * 27 + tap;
            bf16x8 t;
#pragma unroll
            for (int j = 0; j < 8; ++j) t[j] = (__bf16)wp[j * 27];
            af[mt] = __builtin_bit_cast(int4, t);
        }
    };
    auto readB = [&](const char* buf, int ky, int kx, int4* dst) {
#pragma unroll
        for (int nt = 0; nt < 4; ++nt) {
            int wb = nt * 16 + wlo + kx;
            int sl = whi ^ ((wb >> 1) & 3);
            dst[nt] = *(const int4*)(buf + (((row + ky) * 66 + wb) * 64 + sl * 16));
        }
    };

    if (tid < 96) {
        int bu = tid / 48, q2 = tid % 48;
        int y = q2 >> 3, q = q2 & 7;
        int w2 = 64 + (q >> 2), sl = q & 3;
        *(int4*)(xs[bu] + ((y * 66 + w2) * 64 + sl * 16)) = int4{0, 0, 0, 0};
    }
    {
        f32x8 s0 = issueRow(d, 0), s1 = issueRow(d, 1), s2 = issueRow(d, 2);
        writeRow(xs[0], 0, s0); s0 = issueRow(d, 3);
        writeRow(xs[0], 1, s1); s1 = issueRow(d, 4);
        writeRow(xs[0], 2, s2); s2 = issueRow(d, 5);
        writeRow(xs[0], 3, s0); writeRow(xs[0], 4, s1); writeRow(xs[0], 5, s2);
    }
    int4 af[2][4];
    loadA(0, af[0]);
    __syncthreads();

    f32x4 acc[4][4];
#pragma unroll
    for (int mt = 0; mt < 4; ++mt)
#pragma unroll
        for (int nt = 0; nt < 4; ++nt)
            acc[mt][nt] = f32x4{0.f, 0.f, 0.f, 0.f};

    int4 bfr[2][4];

#pragma unroll
    for (int kz = 0; kz < 3; ++kz) {
        char* cur = xs[kz & 1];
        char* nxt = xs[(kz + 1) & 1];
        f32x8 s0, s1, s2;
        readB(cur, 0, 0, bfr[0]);
#pragma unroll
        for (int t = 0; t < 9; ++t) {
            const int T = kz * 9 + t;
            if (T < 26) loadA(T + 1, af[(T + 1) & 1]);
            if (t < 8)  readB(cur, (t + 1) / 3, (t + 1) % 3, bfr[(t + 1) & 1]);
            if (kz < 2) {
                if (t == 3) writeRow(nxt, 0, s0);
                if (t == 4) writeRow(nxt, 1, s1);
                if (t == 5) writeRow(nxt, 2, s2);
                if (t == 6) writeRow(nxt, 3, s0);
                if (t == 7) writeRow(nxt, 4, s1);
                if (t == 8) writeRow(nxt, 5, s2);
                if (t == 0) s0 = issueRow(d + kz + 1, 0);
                if (t == 1) s1 = issueRow(d + kz + 1, 1);
                if (t == 2) s2 = issueRow(d + kz + 1, 2);
                if (t == 3) s0 = issueRow(d + kz + 1, 3);
                if (t == 4) s1 = issueRow(d + kz + 1, 4);
                if (t == 5) s2 = issueRow(d + kz + 1, 5);
            }
#pragma unroll
            for (int mt = 0; mt < 4; ++mt)
#pragma unroll
                for (int nt = 0; nt < 4; ++nt)
                    acc[mt][nt] = __builtin_amdgcn_mfma_f32_16x16x32_bf16(
                        __builtin_bit_cast(bf16x8, af[T & 1][mt]),
                        __builtin_bit_cast(bf16x8, bfr[t & 1][nt]),
                        acc[mt][nt], 0, 0, 0);
        }
        if (kz < 2) __syncthreads();
    }

    const int h = h0 + row;
    if (h < DOUT) {
#pragma unroll
        for (int mt = 0; mt < 4; ++mt) {
#pragma unroll
            for (int r = 0; r < 4; ++r) {
                int oc = mt * 16 + whi * 4 + r;
                size_t ob = ((((size_t)b * OCH + oc) * DOUT + d) * DOUT + h) * DOUT;
#pragma unroll
                for (int nt = 0; nt < 4; ++nt) {
                    int ww = nt * 16 + wlo;
                    if (ww < DOUT) out[ob + ww] = acc[mt][nt][r];
                }
            }
        }
    }
}

extern "C" void kernel_launch(void* const* d_in, const int* in_sizes, int n_in,
                              void* d_out, int out_size, void* d_ws, size_t ws_size,
                              hipStream_t stream) {
    const float* x = (const float*)d_in[0];
    const float* W = (const float*)d_in[1];
    float* out = (float*)d_out;

    const size_t wre_elems = (size_t)27 * OCH * ICH;             // 55,296 ushort
    const size_t xp_elems  = (size_t)2 * DIN * DIN * DIN * ICH;  // 16,777,216 ushort
    const size_t need = (wre_elems + xp_elems) * 2 + 256;

    if (ws_size >= need) {
        unsigned short* Wre3 = (unsigned short*)d_ws;
        unsigned short* xp   = Wre3 + wre_elems;
        prep_all<<<dim3(8192 + 216), 256, 0, stream>>>(x, W, Wre3, xp);
        conv3d_mfma_pk<<<dim3(2 * 31 * 31), 256, 0, stream>>>(Wre3, xp, out);  // 1922 = 8*240+2
    } else {
        conv3d_mfma_fb<<<dim3(2 * DOUT * 16), 256, 0, stream>>>(x, W, out);
    }
}

// Round 24
// 84.254 us; speedup vs baseline: 1.0540x; 1.0123x over previous
//
#include <hip/hip_runtime.h>
#include <hip/hip_bf16.h>

#define DIN 64
#define DOUT 62
#define ICH 32
#define OCH 64

typedef __bf16 bf16x8 __attribute__((ext_vector_type(8)));
typedef float f32x4 __attribute__((ext_vector_type(4)));
typedef float f32x8 __attribute__((ext_vector_type(8)));
typedef float f32x16 __attribute__((ext_vector_type(16)));

#define AS1U(p) ((const __attribute__((address_space(1))) unsigned int*)(p))
#define AS3U(p) ((__attribute__((address_space(3))) unsigned int*)(p))

// ---------- merged prep: one launch does both W and x repack (verified R21) ----------
// Wre3[(((tap*2+mt)*2+kh)*64+lane)*8+j] = bf16( W[oc=mt*32+(lane&31)][ic=kh*16+(lane>>5)*8+j][tap] )
// xp SLICE-MAJOR: xp[b][z][y][s(4)][w(64)][8ic] bf16 (16B packets, fragment-linear).
__global__ void prep_all(const float* __restrict__ x, const float* __restrict__ W,
                         unsigned short* __restrict__ Wre3, unsigned short* __restrict__ xp) {
    const int bid = blockIdx.x;
    if (bid < 8192) {
        int idx = bid * 256 + threadIdx.x;           // 2,097,152 packets
        int w = idx & 63;
        int s = (idx >> 6) & 3;
        int y = (idx >> 8) & 63;
        int z = (idx >> 14) & 63;
        int b = idx >> 20;
        const float* xb = x + ((size_t)(b * ICH + s * 8)) * 262144 + (size_t)z * 4096 + y * 64 + w;
        bf16x8 pk;
#pragma unroll
        for (int j = 0; j < 8; ++j)
            pk[j] = (__bf16)xb[(size_t)j * 262144];
        ((int4*)xp)[idx] = __builtin_bit_cast(int4, pk);
    } else {
        int idx = (bid - 8192) * 256 + threadIdx.x;  // 55,296 elements
        if (idx < 27 * OCH * ICH) {
            int j    = idx & 7;
            int lane = (idx >> 3) & 63;
            int kh   = (idx >> 9) & 1;
            int mt   = (idx >> 10) & 1;
            int tap  = idx >> 11;
            int oc   = mt * 32 + (lane & 31);
            int ic   = kh * 16 + (lane >> 5) * 8 + j;
            float v  = W[((size_t)oc * ICH + ic) * 27 + tap];
            Wre3[idx] = __builtin_bit_cast(unsigned short, (__bf16)v);
        }
    }
}

// ---------- main: R16 exact (replay-verified R16/R17/R18/R21; main ~75.3 us) ----------
// implicit GEMM, 32x32x16 MFMA; block tile (b, d, 4 h-rows) x 64 oc x 64 w; wave = one h row.
// LDS 2 x 24KB planes [y(6)][s(4)][w(64)][16B], linear copy from fragment-linear xp.
// A 2-deep prefetch (coalesced, tap stride 256 int4); B 1-deep from LDS (conflict-free);
// staging interleaved one chunk/wave/tap AFTER loadA (in-order vmcnt discipline).
__global__ __launch_bounds__(256, 3) void conv3d_mfma_pk(
    const unsigned short* __restrict__ Wre3,
    const unsigned short* __restrict__ xp,
    float* __restrict__ out)
{
    __shared__ char xs[2 * 24576 + 256];             // 2 plane bufs + guard

    const int tid  = threadIdx.x;
    const int lane = tid & 63;
    const int wave = tid >> 6;

    // bijective XCD-aware swizzle (nwg = 1984 = 8*248 exactly)
    const int orig = blockIdx.x;
    const int lid  = (orig & 7) * 248 + (orig >> 3);
    const int ht = lid & 15;
    const int rr = lid >> 4;
    const int d  = rr % DOUT;
    const int b  = rr / DOUT;
    const int h0 = ht * 4;

    const int l31 = lane & 31;                       // w-in-tile / oc-in-tile
    const int lhi = lane >> 5;                       // k-subgroup (8 ic) within k-half
    const int row = wave;                            // h row

    auto stage_chunk = [&](char* buf, int z, int i) {
        int c  = wave * 6 + i;                       // 0..23
        int yl = c >> 2;                             // y row 0..5
        int sl = c & 3;                              // ic-slice
        int srow = h0 + yl; if (srow > 63) srow = 63;   // clamped rows feed only discarded h
        const unsigned short* src =
            xp + ((((size_t)(b * DIN + z) * DIN + srow) * 4 + sl) * 64) * 8 + lane * 8;
        __builtin_amdgcn_global_load_lds(AS1U(src), AS3U(buf + c * 1024), 16, 0, 0);
    };
    auto loadA = [&](int tap, int4* af) {            // 4 coalesced dwordx4 (tap stride 256 int4)
        const int4* wp = (const int4*)Wre3 + (size_t)tap * 256 + lane;
#pragma unroll
        for (int q = 0; q < 4; ++q)
            af[q] = wp[q * 64];
    };
    auto readB = [&](const char* buf, int ky, int kx, int4* dst) {   // 4 x ds_read_b128
#pragma unroll
        for (int kh = 0; kh < 2; ++kh) {
            const int g = kh * 2 + lhi;
#pragma unroll
            for (int nt = 0; nt < 2; ++nt) {
                int wb = nt * 32 + l31 + kx;
                if (wb > 63) wb = 63;                // cols 62/63 only (discarded outputs)
                dst[kh * 2 + nt] = *(const int4*)(buf + (((row + ky) * 4 + g) * 64 + wb) * 16);
            }
        }
    };

    char* bufA = xs;
    char* bufB = xs + 24576;

#pragma unroll
    for (int i = 0; i < 6; ++i) stage_chunk(bufA, d, i);   // plane kz=0 (burst, once)
    int4 af[3][4];
    loadA(0, af[0]);
    loadA(1, af[1]);

    f32x16 acc[2][2];
#pragma unroll
    for (int mt = 0; mt < 2; ++mt)
#pragma unroll
        for (int nt = 0; nt < 2; ++nt)
#pragma unroll
            for (int r = 0; r < 16; ++r) acc[mt][nt][r] = 0.f;

    __syncthreads();                                 // plane 0 ready

    int4 bfr[2][4];
    const bool oddw = (wave & 1) != 0;               // wave-uniform branch

#pragma unroll                                        // kz static -> all indices compile-time
    for (int kz = 0; kz < 3; ++kz) {
        char* cur = (kz & 1) ? bufB : bufA;
        char* nxt = (kz & 1) ? bufA : bufB;
        readB(cur, 0, 0, bfr[0]);                    // per-segment B prologue

#pragma unroll
        for (int t = 0; t < 9; ++t) {
            const int T = kz * 9 + t;
            // de-phased issue: even waves A-then-B, odd waves B-then-A
            if (oddw) {
                if (t < 8)  readB(cur, (t + 1) / 3, (t + 1) % 3, bfr[(t + 1) & 1]);
                if (T < 25) loadA(T + 2, af[(T + 2) % 3]);
            } else {
                if (T < 25) loadA(T + 2, af[(T + 2) % 3]);
                if (t < 8)  readB(cur, (t + 1) / 3, (t + 1) % 3, bfr[(t + 1) & 1]);
            }
            if (kz < 2 && t < 6) stage_chunk(nxt, d + kz + 1, t);   // after loads (vmcnt order)

#pragma unroll
            for (int kh = 0; kh < 2; ++kh)           // kh-outer: acc chain distance = 4
#pragma unroll
                for (int mt = 0; mt < 2; ++mt)
#pragma unroll
                    for (int nt = 0; nt < 2; ++nt)
                        acc[mt][nt] = __builtin_amdgcn_mfma_f32_32x32x16_bf16(
                            __builtin_bit_cast(bf16x8, af[T % 3][mt * 2 + kh]),
                            __builtin_bit_cast(bf16x8, bfr[t & 1][kh * 2 + nt]),
                            acc[mt][nt], 0, 0, 0);
        }
        if (kz < 2) __syncthreads();                 // next plane landed; cur free
    }

    // ---- store: D col=lane&31 -> w, row=(r&3)+8*(r>>2)+4*(lane>>5) -> oc ----
    const int h = h0 + row;
    if (h < DOUT) {
#pragma unroll
        for (int mt = 0; mt < 2; ++mt) {
#pragma unroll
            for (int r = 0; r < 16; ++r) {
                int oc = mt * 32 + (r & 3) + 8 * (r >> 2) + 4 * lhi;
                size_t ob = ((((size_t)b * OCH + oc) * DOUT + d) * DOUT + h) * DOUT;
#pragma unroll
                for (int nt = 0; nt < 2; ++nt) {
                    int ww = nt * 32 + l31;
                    if (ww < DOUT) out[ob + ww] = acc[mt][nt][r];
                }
            }
        }
    }
}

// ---------- fallback (ws too small): reg-staged 16x16 kernel, f32 W direct ----------
__global__ __launch_bounds__(256, 3) void conv3d_mfma_fb(
    const float* __restrict__ x, const float* __restrict__ W,
    float* __restrict__ out)
{
    __shared__ char xs[2][6 * 66 * 64];

    const int tid  = threadIdx.x;
    const int lane = tid & 63;
    const int wave = tid >> 6;

    const int orig = blockIdx.x;
    const int lid  = (orig & 7) * 248 + (orig >> 3);
    const int ht = lid & 15;
    const int rr = lid >> 4;
    const int d  = rr % DOUT;
    const int b  = rr / DOUT;
    const int h0 = ht * 4;

    const int wlo = lane & 15;
    const int whi = lane >> 4;
    const int row = wave;

    const int icg  = wave;
    const int w    = lane;
    const int slot = icg ^ ((w >> 1) & 3);

    auto issueRow = [&](int z, int y) -> f32x8 {
        int gy = h0 + y; if (gy > 63) gy = 63;
        const float* xp2 = x + (((size_t)(b * ICH + icg * 8) * DIN + z) * DIN + gy) * DIN + w;
        f32x8 s;
#pragma unroll
        for (int j = 0; j < 8; ++j) s[j] = xp2[(size_t)j * DIN * DIN * DIN];
        return s;
    };
    auto writeRow = [&](char* buf, int y, f32x8 s) {
        bf16x8 pk;
#pragma unroll
        for (int j = 0; j < 8; ++j) pk[j] = (__bf16)s[j];
        *(int4*)(buf + ((y * 66 + w) * 64 + slot * 16)) = __builtin_bit_cast(int4, pk);
    };
    auto loadA = [&](int tap, int4* af) {
#pragma unroll
        for (int mt = 0; mt < 4; ++mt) {
            const float* wp = W + ((size_t)(mt * 16 + wlo) * ICH + whi * 8) * 27 + tap;
            bf16x8 t;
#pragma unroll
            for (int j = 0; j < 8; ++j) t[j] = (__bf16)wp[j * 27];
            af[mt] = __builtin_bit_cast(int4, t);
        }
    };
    auto readB = [&](const char* buf, int ky, int kx, int4* dst) {
#pragma unroll
        for (int nt = 0; nt < 4; ++nt) {
            int wb = nt * 16 + wlo + kx;
            int sl = whi ^ ((wb >> 1) & 3);
            dst[nt] = *(const int4*)(buf + (((row + ky) * 66 + wb) * 64 + sl * 16));
        }
    };

    if (tid < 96) {
        int bu = tid / 48, q2 = tid % 48;
        int y = q2 >> 3, q = q2 & 7;
        int w2 = 64 + (q >> 2), sl = q & 3;
        *(int4*)(xs[bu] + ((y * 66 + w2) * 64 + sl * 16)) = int4{0, 0, 0, 0};
    }
    {
        f32x8 s0 = issueRow(d, 0), s1 = issueRow(d, 1), s2 = issueRow(d, 2);
        writeRow(xs[0], 0, s0); s0 = issueRow(d, 3);
        writeRow(xs[0], 1, s1); s1 = issueRow(d, 4);
        writeRow(xs[0], 2, s2); s2 = issueRow(d, 5);
        writeRow(xs[0], 3, s0); writeRow(xs[0], 4, s1); writeRow(xs[0], 5, s2);
    }
    int4 af[2][4];
    loadA(0, af[0]);
    __syncthreads();

    f32x4 acc[4][4];
#pragma unroll
    for (int mt = 0; mt < 4; ++mt)
#pragma unroll
        for (int nt = 0; nt < 4; ++nt)
            acc[mt][nt] = f32x4{0.f, 0.f, 0.f, 0.f};

    int4 bfr[2][4];

#pragma unroll
    for (int kz = 0; kz < 3; ++kz) {
        char* cur = xs[kz & 1];
        char* nxt = xs[(kz + 1) & 1];
        f32x8 s0, s1, s2;
        readB(cur, 0, 0, bfr[0]);
#pragma unroll
        for (int t = 0; t < 9; ++t) {
            const int T = kz * 9 + t;
            if (T < 26) loadA(T + 1, af[(T + 1) & 1]);
            if (t < 8)  readB(cur, (t + 1) / 3, (t + 1) % 3, bfr[(t + 1) & 1]);
            if (kz < 2) {
                if (t == 3) writeRow(nxt, 0, s0);
                if (t == 4) writeRow(nxt, 1, s1);
                if (t == 5) writeRow(nxt, 2, s2);
                if (t == 6) writeRow(nxt, 3, s0);
                if (t == 7) writeRow(nxt, 4, s1);
                if (t == 8) writeRow(nxt, 5, s2);
                if (t == 0) s0 = issueRow(d + kz + 1, 0);
                if (t == 1) s1 = issueRow(d + kz + 1, 1);
                if (t == 2) s2 = issueRow(d + kz + 1, 2);
                if (t == 3) s0 = issueRow(d + kz + 1, 3);
                if (t == 4) s1 = issueRow(d + kz + 1, 4);
                if (t == 5) s2 = issueRow(d + kz + 1, 5);
            }
#pragma unroll
            for (int mt = 0; mt < 4; ++mt)
#pragma unroll
                for (int nt = 0; nt < 4; ++nt)
                    acc[mt][nt] = __builtin_amdgcn_mfma_f32_16x16x32_bf16(
                        __builtin_bit_cast(bf16x8, af[T & 1][mt]),
                        __builtin_bit_cast(bf16x8, bfr[t & 1][nt]),
                        acc[mt][nt], 0, 0, 0);
        }
        if (kz < 2) __syncthreads();
    }

    const int h = h0 + row;
    if (h < DOUT) {
#pragma unroll
        for (int mt = 0; mt < 4; ++mt) {
#pragma unroll
            for (int r = 0; r < 4; ++r) {
                int oc = mt * 16 + whi * 4 + r;
                size_t ob = ((((size_t)b * OCH + oc) * DOUT + d) * DOUT + h) * DOUT;
#pragma unroll
                for (int nt = 0; nt < 4; ++nt) {
                    int ww = nt * 16 + wlo;
                    if (ww < DOUT) out[ob + ww] = acc[mt][nt][r];
                }
            }
        }
    }
}

extern "C" void kernel_launch(void* const* d_in, const int* in_sizes, int n_in,
                              void* d_out, int out_size, void* d_ws, size_t ws_size,
                              hipStream_t stream) {
    const float* x = (const float*)d_in[0];
    const float* W = (const float*)d_in[1];
    float* out = (float*)d_out;

    const size_t wre_elems = (size_t)27 * OCH * ICH;             // 55,296 ushort
    const size_t xp_elems  = (size_t)2 * DIN * DIN * DIN * ICH;  // 16,777,216 ushort
    const size_t need = (wre_elems + xp_elems) * 2 + 256;

    if (ws_size >= need) {
        unsigned short* Wre3 = (unsigned short*)d_ws;
        unsigned short* xp   = Wre3 + wre_elems;
        prep_all<<<dim3(8192 + 216), 256, 0, stream>>>(x, W, Wre3, xp);
        conv3d_mfma_pk<<<dim3(2 * DOUT * 16), 256, 0, stream>>>(Wre3, xp, out);  // 1984 = 8*248
    } else {
        conv3d_mfma_fb<<<dim3(2 * DOUT * 16), 256, 0, stream>>>(x, W, out);
    }
}